// Round 4
// baseline (238.566 us; speedup 1.0000x reference)
//
#include <hip/hip_runtime.h>
#include <math.h>

#define N_DIM 4
#define C_DIM 4096
#define EPSF 1e-6f
#define TPB 1024   // one float4 chunk per thread per stream: C_DIM/4 == TPB

typedef float f32x4 __attribute__((ext_vector_type(4)));

// One block per batch row b. 1024 threads; each thread owns ONE float4 chunk
// (4 c-values) per stream n -> whole 4x4096 fp32 row in block registers,
// minimal per-thread VGPR state -> max occupancy for barrier-latency hiding.
__global__ __launch_bounds__(TPB) void mhc_fused_kernel(
    const float* __restrict__ x,      // [B, 4, 4096]
    const float* __restrict__ H_pre,  // [4]
    const float* __restrict__ H_post, // [4]
    const float* __restrict__ H_res,  // [4,4]
    const float* __restrict__ w,      // [4096]
    float* __restrict__ out)          // [B, 4, 4096]
{
    __shared__ float sRed[TPB / 64];

    const int b = blockIdx.x;
    const int t = threadIdx.x;

    const f32x4* x4 = reinterpret_cast<const f32x4*>(x + (size_t)b * (N_DIM * C_DIM));
    const f32x4* w4 = reinterpret_cast<const f32x4*>(w);

    // ---- issue streaming loads first (latency hides the scalar math below) ----
    f32x4 xv[4];   // one chunk per stream n
#pragma unroll
    for (int n = 0; n < 4; ++n)
        xv[n] = __builtin_nontemporal_load(&x4[n * (C_DIM / 4) + t]);

    f32x4 wv = w4[t];   // reused by every block -> temporal load

    // ---- gates + sinkhorn, computed redundantly by every thread (uniform) ----
    float pre[4], post[4], P[4][4];
#pragma unroll
    for (int n = 0; n < 4; ++n) {
        pre[n]  = 1.0f / (1.0f + expf(-H_pre[n]));
        post[n] = 2.0f / (1.0f + expf(-H_post[n]));
    }
#pragma unroll
    for (int i = 0; i < 4; ++i)
#pragma unroll
        for (int j = 0; j < 4; ++j)
            P[i][j] = expf(H_res[i * 4 + j]);
#pragma unroll
    for (int it = 0; it < 3; ++it) {
#pragma unroll
        for (int i = 0; i < 4; ++i) {           // row normalize (axis -1)
            float r = 1.0f / (P[i][0] + P[i][1] + P[i][2] + P[i][3] + EPSF);
#pragma unroll
            for (int j = 0; j < 4; ++j) P[i][j] *= r;
        }
#pragma unroll
        for (int j = 0; j < 4; ++j) {           // column normalize (axis -2)
            float r = 1.0f / (P[0][j] + P[1][j] + P[2][j] + P[3][j] + EPSF);
#pragma unroll
            for (int i = 0; i < 4; ++i) P[i][j] *= r;
        }
    }

    // ---- gated aggregate + local sum of squares ----
    f32x4 agg = pre[0] * xv[0] + pre[1] * xv[1] + pre[2] * xv[2] + pre[3] * xv[3];
    float ssq = agg.x * agg.x + agg.y * agg.y + agg.z * agg.z + agg.w * agg.w;

    // ---- block reduction of ssq over the 4096 c-values (16 waves) ----
#pragma unroll
    for (int off = 32; off > 0; off >>= 1)
        ssq += __shfl_down(ssq, off);
    if ((t & 63) == 0) sRed[t >> 6] = ssq;
    __syncthreads();
    float tot = 0.0f;
#pragma unroll
    for (int k = 0; k < TPB / 64; ++k) tot += sRed[k];
    float inv_rms = rsqrtf(tot * (1.0f / (float)C_DIM) + EPSF);

    // ---- mix streams + post-gated RMS-normed aggregate; streaming store ----
    f32x4* o4 = reinterpret_cast<f32x4*>(out + (size_t)b * (N_DIM * C_DIM));
    f32x4 nrm = agg * wv * inv_rms;
#pragma unroll
    for (int m = 0; m < 4; ++m) {
        f32x4 o = P[m][0] * xv[0] + P[m][1] * xv[1] + P[m][2] * xv[2] + P[m][3] * xv[3]
                + post[m] * nrm;
        __builtin_nontemporal_store(o, &o4[m * (C_DIM / 4) + t]);
    }
}

extern "C" void kernel_launch(void* const* d_in, const int* in_sizes, int n_in,
                              void* d_out, int out_size, void* d_ws, size_t ws_size,
                              hipStream_t stream) {
    const float* x      = (const float*)d_in[0];
    const float* H_pre  = (const float*)d_in[1];
    const float* H_post = (const float*)d_in[2];
    const float* H_res  = (const float*)d_in[3];
    const float* w      = (const float*)d_in[4];
    float* out = (float*)d_out;

    const int B = in_sizes[0] / (N_DIM * C_DIM);
    hipLaunchKernelGGL(mhc_fused_kernel, dim3(B), dim3(TPB), 0, stream,
                       x, H_pre, H_post, H_res, w, out);
}

// Round 5
// 179.626 us; speedup vs baseline: 1.3281x; 1.3281x over previous
//
#include <hip/hip_runtime.h>
#include <math.h>

#define N_DIM 4
#define C_DIM 4096
#define EPSF 1e-6f
#define TPB 256
#define CHUNKS 4   // (C_DIM/4) float4 per stream / TPB threads

typedef float f32x4 __attribute__((ext_vector_type(4)));

// One block per batch row b. 256 threads (4 waves); each thread owns 4 float4
// chunks (16 c-values) per stream n -> 16 nt-loads in flight per thread,
// narrow 4-wave barrier group. agg recomputed after the barrier to minimize
// cross-barrier live registers.
__global__ __launch_bounds__(TPB) void mhc_fused_kernel(
    const float* __restrict__ x,      // [B, 4, 4096]
    const float* __restrict__ H_pre,  // [4]
    const float* __restrict__ H_post, // [4]
    const float* __restrict__ H_res,  // [4,4]
    const float* __restrict__ w,      // [4096]
    float* __restrict__ out)          // [B, 4, 4096]
{
    __shared__ float sRed[TPB / 64];

    const int b = blockIdx.x;
    const int t = threadIdx.x;

    const f32x4* x4 = reinterpret_cast<const f32x4*>(x + (size_t)b * (N_DIM * C_DIM));
    const f32x4* w4 = reinterpret_cast<const f32x4*>(w);

    // ---- issue all streaming loads first ----
    f32x4 xv[CHUNKS][4];   // [chunk][stream n]
#pragma unroll
    for (int i = 0; i < CHUNKS; ++i)
#pragma unroll
        for (int n = 0; n < 4; ++n)
            xv[i][n] = __builtin_nontemporal_load(&x4[n * (C_DIM / 4) + i * TPB + t]);

    f32x4 wv[CHUNKS];      // reused by every block -> temporal load
#pragma unroll
    for (int i = 0; i < CHUNKS; ++i)
        wv[i] = w4[i * TPB + t];

    // ---- gates + sinkhorn, computed redundantly by every thread (uniform) ----
    float pre[4], post[4], P[4][4];
#pragma unroll
    for (int n = 0; n < 4; ++n) {
        pre[n]  = 1.0f / (1.0f + expf(-H_pre[n]));
        post[n] = 2.0f / (1.0f + expf(-H_post[n]));
    }
#pragma unroll
    for (int i = 0; i < 4; ++i)
#pragma unroll
        for (int j = 0; j < 4; ++j)
            P[i][j] = expf(H_res[i * 4 + j]);
#pragma unroll
    for (int it = 0; it < 3; ++it) {
#pragma unroll
        for (int i = 0; i < 4; ++i) {           // row normalize (axis -1)
            float r = 1.0f / (P[i][0] + P[i][1] + P[i][2] + P[i][3] + EPSF);
#pragma unroll
            for (int j = 0; j < 4; ++j) P[i][j] *= r;
        }
#pragma unroll
        for (int j = 0; j < 4; ++j) {           // column normalize (axis -2)
            float r = 1.0f / (P[0][j] + P[1][j] + P[2][j] + P[3][j] + EPSF);
#pragma unroll
            for (int i = 0; i < 4; ++i) P[i][j] *= r;
        }
    }

    // ---- gated aggregate -> local sum of squares (agg NOT kept live) ----
    float ssq = 0.0f;
#pragma unroll
    for (int i = 0; i < CHUNKS; ++i) {
        f32x4 a = pre[0] * xv[i][0] + pre[1] * xv[i][1] + pre[2] * xv[i][2] + pre[3] * xv[i][3];
        ssq += a.x * a.x + a.y * a.y + a.z * a.z + a.w * a.w;
    }

    // ---- block reduction of ssq (4 waves) ----
#pragma unroll
    for (int off = 32; off > 0; off >>= 1)
        ssq += __shfl_down(ssq, off);
    if ((t & 63) == 0) sRed[t >> 6] = ssq;
    __syncthreads();
    float tot = 0.0f;
#pragma unroll
    for (int k = 0; k < TPB / 64; ++k) tot += sRed[k];
    float inv_rms = rsqrtf(tot * (1.0f / (float)C_DIM) + EPSF);

    // ---- mix streams + post-gated RMS-normed aggregate; streaming store ----
    f32x4* o4 = reinterpret_cast<f32x4*>(out + (size_t)b * (N_DIM * C_DIM));
#pragma unroll
    for (int i = 0; i < CHUNKS; ++i) {
        // recompute aggregate from xv (cheap VALU; keeps live set small)
        f32x4 a = pre[0] * xv[i][0] + pre[1] * xv[i][1] + pre[2] * xv[i][2] + pre[3] * xv[i][3];
        f32x4 nrm = (a * wv[i]) * inv_rms;
#pragma unroll
        for (int m = 0; m < 4; ++m) {
            f32x4 o = P[m][0] * xv[i][0] + P[m][1] * xv[i][1] + P[m][2] * xv[i][2] + P[m][3] * xv[i][3]
                    + post[m] * nrm;
            __builtin_nontemporal_store(o, &o4[m * (C_DIM / 4) + i * TPB + t]);
        }
    }
}

extern "C" void kernel_launch(void* const* d_in, const int* in_sizes, int n_in,
                              void* d_out, int out_size, void* d_ws, size_t ws_size,
                              hipStream_t stream) {
    const float* x      = (const float*)d_in[0];
    const float* H_pre  = (const float*)d_in[1];
    const float* H_post = (const float*)d_in[2];
    const float* H_res  = (const float*)d_in[3];
    const float* w      = (const float*)d_in[4];
    float* out = (float*)d_out;

    const int B = in_sizes[0] / (N_DIM * C_DIM);
    hipLaunchKernelGGL(mhc_fused_kernel, dim3(B), dim3(TPB), 0, stream,
                       x, H_pre, H_post, H_res, w, out);
}